// Round 5
// baseline (168.663 us; speedup 1.0000x reference)
//
#include <hip/hip_runtime.h>

// SLAYER SNN forward, MI355X. Round 5.
// k1: conv1+pool1 as 8x8-tap stride-4 conv. 1-wave blocks, 4 frames/wave,
//     thread=(i,jh) computes 4c x 4j outputs. Weights folded IN-BLOCK into LDS
//     (broadcast ds_read in the loop -- round-4's per-iteration s_load stall
//     chains removed). Both cin staged upfront (one barrier, one exposure).
// k2: PSP+refractory scan, single 100-deep load batch.
// k3: conv2+pool2 as 4x4 stride-2 conv; wl2 folded in-block.
// k45: scan2 + dense fused (unchanged from round 4).
// FP32; all summation expression trees bit-identical to round 4 (absmax 0.0).

#define DECAY 0.9048374180359595f   // exp(-1/10)

// ---------------- k1: conv1+pool1, 8x8-tap stride-4 ----------------
// grid 1600 x 64. Tile: [fr][cin][36 prow x 36 col], perm(r)=(r&3)*9+(r>>2).
// Logical x row R (-2..33) at prow perm(R+2); col C (-2..33) at phys C+2.
// Halo rows r{0,1,34,35} -> prows {0,9,26,35}; halo cols phys {0,1,34,35}.
__global__ __launch_bounds__(64) void k1(const float* __restrict__ x,
        const float* __restrict__ w1, const float* __restrict__ wp1,
        float* __restrict__ u1) {
    __shared__ __align__(16) float xs[8 * 1296];   // 41.5 KB
    __shared__ __align__(16) float wl[512];        // [(cin*8+e)*32 + c*8 + f]
    const int lane = threadIdx.x;
    const int fr = lane >> 4, l4 = lane & 15;
    const int i = (lane >> 1) & 7, jh = lane & 1;  // l4 = i*2 + jh
    const int frame = blockIdx.x * 4 + fr;         // = n*100 + t (x is n-major)
    const int n = frame / 100, t = frame % 100;

    // fold weights into LDS: 8 elements/lane
    const float p1 = wp1[0];
    #pragma unroll
    for (int q = 0; q < 8; ++q) {
        const int idx = lane + 64 * q;
        const int f = idx & 7, c = (idx >> 3) & 3, e = (idx >> 5) & 7, cin = idx >> 8;
        const int cc = c * 2 + cin;
        int alo = e - 3; if (alo < 0) alo = 0;
        int ahi = e;     if (ahi > 4) ahi = 4;
        int blo = f - 3; if (blo < 0) blo = 0;
        int bhi = f;     if (bhi > 4) bhi = 4;
        float s = 0.f;
        for (int a = alo; a <= ahi; ++a)
            for (int b = blo; b <= bhi; ++b)
                s += w1[cc * 25 + a * 5 + b];
        wl[(cin * 8 + e) * 32 + c * 8 + f] = s * p1;
    }

    // zero halo rows: 8 tiles x 4 prows {0,9,26,35} x 9 float4
    #pragma unroll
    for (int m0 = 0; m0 < 288; m0 += 64) {
        const int m = m0 + lane;
        if (m < 288) {
            const int tl = m / 36, rem = m % 36;
            const int rr = rem / 9, q4 = rem % 9;
            const int pr = (rr == 0) ? 0 : (rr == 1) ? 9 : (rr == 2) ? 26 : 35;
            *(float4*)(xs + tl * 1296 + pr * 36 + q4 * 4) = make_float4(0.f, 0.f, 0.f, 0.f);
        }
    }
    // zero halo cols: 8 tiles x 36 prows x 2 sides (float2 at phys 0 / 34)
    #pragma unroll
    for (int m0 = 0; m0 < 576; m0 += 64) {
        const int m = m0 + lane;
        const int tl = m / 72, rem = m % 72;
        const int side = rem & 1, pr = rem >> 1;
        *(float2*)(xs + tl * 1296 + pr * 36 + side * 34) = make_float2(0.f, 0.f);
    }

    // stage both cin (2048 floats/frame; 16 lanes/frame, 32 float4 each)
    const float4* xg = (const float4*)(x + (size_t)frame * 2048);
    #pragma unroll
    for (int q = 0; q < 32; ++q) {
        const int m = q * 16 + l4;                 // float4 idx 0..511
        const float4 v = xg[m];
        const int li = 4 * m;
        const int cin = li >> 10, row = (li >> 5) & 31, col = li & 31;
        const int r = row + 2;
        const int pr = (r & 3) * 9 + (r >> 2);
        float* d = xs + (fr * 2 + cin) * 1296 + pr * 36 + col + 2;
        *(float2*)(d)     = make_float2(v.x, v.y);
        *(float2*)(d + 2) = make_float2(v.z, v.w);
    }
    __syncthreads();

    float acc[4][4] = {{0.f}};   // [c][jj]
    const float* tb = xs + fr * 2592 + i * 36 + jh * 16;
    #pragma unroll
    for (int cin = 0; cin < 2; ++cin) {
        #pragma unroll
        for (int e = 0; e < 8; ++e) {
            // x row 4i+e-2 -> prow (e&3)*9 + (e>>2) + i  (the +i is in tb)
            const int ro = cin * 1296 + ((e & 3) * 9 + (e >> 2)) * 36;
            float xr[20];
            #pragma unroll
            for (int b = 0; b < 5; ++b)
                *(float4*)(xr + 4 * b) = *(const float4*)(tb + ro + 4 * b);
            const float* wp = wl + (cin * 8 + e) * 32;
            float wr_[32];
            #pragma unroll
            for (int q = 0; q < 8; ++q)
                *(float4*)(wr_ + 4 * q) = *(const float4*)(wp + 4 * q);
            #pragma unroll
            for (int c = 0; c < 4; ++c) {
                #pragma unroll
                for (int jj = 0; jj < 4; ++jj) {
                    const int o = 4 * jj;
                    acc[c][jj] += xr[o]*wr_[c*8]     + xr[o+1]*wr_[c*8+1]
                                + xr[o+2]*wr_[c*8+2] + xr[o+3]*wr_[c*8+3]
                                + xr[o+4]*wr_[c*8+4] + xr[o+5]*wr_[c*8+5]
                                + xr[o+6]*wr_[c*8+6] + xr[o+7]*wr_[c*8+7];
                }
            }
        }
    }

    float* ob = u1 + (size_t)t * 16384 + n * 256 + i * 8 + jh * 4;
    #pragma unroll
    for (int c = 0; c < 4; ++c)
        *(float4*)(ob + c * 64) = make_float4(acc[c][0], acc[c][1], acc[c][2], acc[c][3]);
}

// ---------------- k2: scan1, single 100-deep batch, in-place ----------------
__global__ __launch_bounds__(64) void k2_scan(float* __restrict__ u) {
    const int id = blockIdx.x * 64 + threadIdx.x;
    const float a = DECAY;
    float* p = u + id;
    float v[100];
    #pragma unroll
    for (int k = 0; k < 100; ++k) v[k] = p[(size_t)k * 16384];
    float psp = 0.f, r = 0.f;
    #pragma unroll
    for (int k = 0; k < 100; ++k) {
        psp = a * psp + v[k];
        const float vv = psp - r;
        const float s = (vv >= 1.f) ? 1.f : 0.f;
        r = a * (r + s);
        p[(size_t)k * 16384] = s;
    }
}

// ---------------- k3: conv2+pool2 as 4x4 stride-2 conv ----------------
// 8 frames/block (32 thr each); wl2 folded in-block.
__global__ __launch_bounds__(256) void k3(const float* __restrict__ s1,
        const float* __restrict__ w2, const float* __restrict__ wp2,
        float* __restrict__ u2) {
    __shared__ __align__(16) float xs[8 * 660];
    __shared__ __align__(16) float wl[544];
    const int tid = threadIdx.x, sub = tid >> 5, l = tid & 31;

    // fold weights: 2 elements/thread
    const float p2 = wp2[0];
    #pragma unroll
    for (int q = 0; q < 2; ++q) {
        const int idx = tid + 256 * q;
        const int c2 = idx & 7, f = (idx >> 3) & 3, e = (idx >> 5) & 3, cin = idx >> 7;
        int alo = e - 1; if (alo < 0) alo = 0;
        int ahi = e;     if (ahi > 2) ahi = 2;
        int blo = f - 1; if (blo < 0) blo = 0;
        int bhi = f;     if (bhi > 2) bhi = 2;
        float s = 0.f;
        for (int aa = alo; aa <= ahi; ++aa)
            for (int bb = blo; bb <= bhi; ++bb)
                s += w2[((c2 * 4 + cin) * 3 + aa) * 3 + bb];
        wl[c2 * 68 + cin * 16 + e * 4 + f] = s * p2;
    }

    float* xt = xs + sub * 660;
    float4* fz = (float4*)xt;
    for (int m = l; m < 160; m += 32) fz[m] = make_float4(0.f, 0.f, 0.f, 0.f);

    const int frame = blockIdx.x * 8 + sub;       // = t*64 + n (s1 is t-major)
    const int t = frame >> 6, n = frame & 63;
    const float* fr = s1 + (size_t)t * 16384 + n * 256;
    {   // stage 8x8x4cin; row r=row+1 at perm(r)=(r&1)*5+(r>>1), cols +4 phys
        const int cin = l >> 3, row = l & 7;
        const int r = row + 1;
        const int pr = (r & 1) * 5 + (r >> 1);
        const float4 v0 = *(const float4*)(fr + cin * 64 + row * 8);
        const float4 v1 = *(const float4*)(fr + cin * 64 + row * 8 + 4);
        *(float4*)(xt + cin * 160 + pr * 16 + 4) = v0;
        *(float4*)(xt + cin * 160 + pr * 16 + 8) = v1;
    }
    __syncthreads();

    const int c2 = l >> 2, i = l & 3;
    float acc[4] = {0.f, 0.f, 0.f, 0.f};
    const float* wb = wl + c2 * 68;
    const float* tb = xt + i * 16;
    #pragma unroll
    for (int cin = 0; cin < 4; ++cin) {
        #pragma unroll
        for (int e = 0; e < 4; ++e) {
            const int C = cin * 160 + ((e & 1) * 5 + (e >> 1)) * 16;
            float xr[16];
            #pragma unroll
            for (int b = 0; b < 4; ++b)
                *(float4*)(xr + 4 * b) = *(const float4*)(tb + C + 4 * b);
            float wv[4];
            *(float4*)(wv) = *(const float4*)(wb + cin * 16 + e * 4);
            #pragma unroll
            for (int j = 0; j < 4; ++j) {
                #pragma unroll
                for (int f = 0; f < 4; ++f)
                    acc[j] += xr[2 * j + f + 3] * wv[f];
            }
        }
    }
    *(float4*)(u2 + (size_t)t * 8192 + n * 128 + c2 * 16 + i * 4) =
        make_float4(acc[0], acc[1], acc[2], acc[3]);
}

// ---------------- k45: scan2 + dense, fused ----------------
// one block per n (64 blocks x 128 thr). Spikes stay in LDS; exact shuffle tree.
__global__ __launch_bounds__(128, 2) void k45(const float* __restrict__ u2,
        const float* __restrict__ lw, float* __restrict__ out) {
    __shared__ float ls[25 * 128];
    const int f = threadIdx.x, n = blockIdx.x;
    const int wave = f >> 6, l = f & 63;
    const float a = DECAY;
    const float w0 = lw[l], w1v = lw[64 + l], w2v = lw[128 + l], w3v = lw[192 + l];
    float psp = 0.f, r = 0.f;
    const float* p = u2 + n * 128 + f;
    #pragma unroll 1
    for (int t0 = 0; t0 < 100; t0 += 25) {
        float v[25];
        #pragma unroll
        for (int k = 0; k < 25; ++k) v[k] = p[(size_t)(t0 + k) * 8192];
        #pragma unroll
        for (int k = 0; k < 25; ++k) {
            psp = a * psp + v[k];
            const float vv = psp - r;
            const float s = (vv >= 1.f) ? 1.f : 0.f;
            r = a * (r + s);
            ls[k * 128 + f] = s;
        }
        __syncthreads();
        const int base = wave ? 13 : 0, cnt = wave ? 12 : 13;
        for (int q = 0; q < cnt; ++q) {
            const int k = base + q;
            const float sa = ls[k * 128 + l], sb = ls[k * 128 + 64 + l];
            float a0 = sa * w0 + sb * w1v;
            float a1 = sa * w2v + sb * w3v;
            #pragma unroll
            for (int off = 32; off > 0; off >>= 1) {
                a0 += __shfl_down(a0, off);
                a1 += __shfl_down(a1, off);
            }
            if (l == 0) {
                const int tt = t0 + k;
                out[n * 200 + tt * 2]     = a0;
                out[n * 200 + tt * 2 + 1] = a1;
            }
        }
        __syncthreads();
    }
}

extern "C" void kernel_launch(void* const* d_in, const int* in_sizes, int n_in,
                              void* d_out, int out_size, void* d_ws, size_t ws_size,
                              hipStream_t stream) {
    const float* x   = (const float*)d_in[0];
    const float* w1  = (const float*)d_in[1];
    const float* w2  = (const float*)d_in[2];
    const float* lw  = (const float*)d_in[3];
    const float* wp1 = (const float*)d_in[4];
    const float* wp2 = (const float*)d_in[5];

    float* u1  = (float*)d_ws;           // 1,638,400 floats (in-place -> s1)
    float* u2  = u1 + 1638400;           //   819,200 floats (pre-scan only)
    float* out = (float*)d_out;          // (64,100,2)

    k1<<<1600, 64, 0, stream>>>(x, w1, wp1, u1);
    k2_scan<<<256, 64, 0, stream>>>(u1);
    k3<<<800, 256, 0, stream>>>(u1, w2, wp2, u2);
    k45<<<64, 128, 0, stream>>>(u2, lw, out);
}

// Round 6
// 143.598 us; speedup vs baseline: 1.1745x; 1.1745x over previous
//
#include <hip/hip_runtime.h>

// SLAYER SNN forward, MI355X. Round 6.
// Lesson R2-R5: k1 variants with <8 waves/CU are latency-bound at ~50 us no
// matter how lean the instruction stream. Fix = R1's occupancy + R5's inner loop:
// k0: fold conv+pool weights once (1 block) -> wl1 (8x8 stride-4 taps), wl2.
// k1: 6400 one-wave blocks (1 frame each, 25 blocks/CU, ~12 resident via
//     12.4 KB LDS). thread=(c,i,jh), 4 outputs, ds_read_b128 inner loop,
//     2-way-max LDS bank aliasing (free), folded weights loaded coalesced.
// k2: PSP+refractory scan, single 100-deep batch (structural 256 waves).
// k3: conv2+pool2 as 4x4 stride-2 conv, weights from k0 (R4 version).
// k45: scan2 + dense fused (unchanged).
// FP32; all summation expression trees bit-identical to rounds 4-5 (absmax 0.0).

#define DECAY 0.9048374180359595f   // exp(-1/10)

// ---------------- k0: fold weights ----------------
// wl1[(cin*8 + e)*32 + c*8 + f], e,f in 0..7  (512 floats)
// wl2[c2*68 + cin*16 + e*4 + f]               (544 floats incl. unused pads)
__global__ __launch_bounds__(128) void k0_fold(const float* __restrict__ w1,
        const float* __restrict__ w2, const float* __restrict__ wp1,
        const float* __restrict__ wp2, float* __restrict__ wl1,
        float* __restrict__ wl2) {
    const int tid = threadIdx.x;
    const float p1 = wp1[0], p2 = wp2[0];
    for (int idx = tid; idx < 512; idx += 128) {
        const int f = idx & 7, c = (idx >> 3) & 3, e = (idx >> 5) & 7, cin = idx >> 8;
        const int cc = c * 2 + cin;
        int alo = e - 3; if (alo < 0) alo = 0;
        int ahi = e;     if (ahi > 4) ahi = 4;
        int blo = f - 3; if (blo < 0) blo = 0;
        int bhi = f;     if (bhi > 4) bhi = 4;
        float s = 0.f;
        for (int a = alo; a <= ahi; ++a)
            for (int b = blo; b <= bhi; ++b)
                s += w1[cc * 25 + a * 5 + b];
        wl1[(cin * 8 + e) * 32 + c * 8 + f] = s * p1;
    }
    for (int idx = tid; idx < 512; idx += 128) {
        const int c2 = idx & 7, f = (idx >> 3) & 3, e = (idx >> 5) & 3, cin = idx >> 7;
        int alo = e - 1; if (alo < 0) alo = 0;
        int ahi = e;     if (ahi > 2) ahi = 2;
        int blo = f - 1; if (blo < 0) blo = 0;
        int bhi = f;     if (bhi > 2) bhi = 2;
        float s = 0.f;
        for (int aa = alo; aa <= ahi; ++aa)
            for (int bb = blo; bb <= bhi; ++bb)
                s += w2[((c2 * 4 + cin) * 3 + aa) * 3 + bb];
        wl2[c2 * 68 + cin * 16 + e * 4 + f] = s * p2;
    }
}

// ---------------- k1: conv1+pool1, 8x8-tap stride-4 ----------------
// grid 6400 x 64, one frame per block. Tile: [cin][36 prow x 36 col],
// perm(r)=(r&3)*9+(r>>2) bijective on r=0..35. Logical x row R (-2..33) at
// prow perm(R+2); logical col C (-2..33) at phys col C+2.
// Halo rows r{0,1,34,35} -> prows {0,9,26,35}; halo cols phys {0,1},{34,35}.
__global__ __launch_bounds__(64) void k1(const float* __restrict__ x,
        const float* __restrict__ wg, float* __restrict__ u1) {
    __shared__ __align__(16) float xs[2 * 1296];   // 10.1 KB
    __shared__ __align__(16) float wl[512];        // 2 KB
    const int lane = threadIdx.x;
    const int c = lane >> 4, i = (lane >> 1) & 7, jh = lane & 1;
    const int frame = blockIdx.x;                  // = n*100 + t (x is n-major)
    const int n = frame / 100, t = frame % 100;

    // folded weights global->LDS, coalesced (2 float4/lane)
    *(float4*)(wl + 4 * lane)       = *(const float4*)(wg + 4 * lane);
    *(float4*)(wl + 256 + 4 * lane) = *(const float4*)(wg + 256 + 4 * lane);

    // zero halo rows: 2 cin x prows {0,9,26,35} x 9 float4 = 72 float4
    #pragma unroll
    for (int m0 = 0; m0 < 128; m0 += 64) {
        const int m = m0 + lane;
        if (m < 72) {
            const int cin = m / 36, rem = m % 36;
            const int rr = rem / 9, q4 = rem % 9;
            const int pr = (rr == 0) ? 0 : (rr == 1) ? 9 : (rr == 2) ? 26 : 35;
            *(float4*)(xs + cin * 1296 + pr * 36 + q4 * 4) = make_float4(0.f, 0.f, 0.f, 0.f);
        }
    }
    // zero halo cols: 2 cin x 36 prows x 2 sides (float2 at phys col 0 / 34)
    #pragma unroll
    for (int m0 = 0; m0 < 192; m0 += 64) {
        const int m = m0 + lane;
        if (m < 144) {
            const int cin = m / 72, rem = m % 72;
            const int side = rem & 1, pr = rem >> 1;
            *(float2*)(xs + cin * 1296 + pr * 36 + side * 34) = make_float2(0.f, 0.f);
        }
    }
    // stage frame: 512 float4, 8 per lane, coalesced
    const float4* xg = (const float4*)(x + (size_t)frame * 2048);
    #pragma unroll
    for (int q = 0; q < 8; ++q) {
        const int m = q * 64 + lane;
        const float4 v = xg[m];
        const int li = 4 * m;
        const int cin = li >> 10, row = (li >> 5) & 31, col = li & 31;
        const int r = row + 2;
        const int pr = (r & 3) * 9 + (r >> 2);
        float* d = xs + cin * 1296 + pr * 36 + col + 2;
        *(float2*)(d)     = make_float2(v.x, v.y);
        *(float2*)(d + 2) = make_float2(v.z, v.w);
    }
    __syncthreads();

    // outputs (c, i, j=4*jh+jj): x phys cols 4j..4j+7, rows prow((e&3)*9+(e>>2))+i
    float acc[4] = {0.f, 0.f, 0.f, 0.f};
    const float* tb = xs + i * 36 + jh * 16;
    #pragma unroll
    for (int cin = 0; cin < 2; ++cin) {
        #pragma unroll
        for (int e = 0; e < 8; ++e) {
            const int ro = cin * 1296 + ((e & 3) * 9 + (e >> 2)) * 36;
            float xr[20];
            #pragma unroll
            for (int b = 0; b < 5; ++b)
                *(float4*)(xr + 4 * b) = *(const float4*)(tb + ro + 4 * b);
            float wv[8];
            *(float4*)(wv)     = *(const float4*)(wl + (cin * 8 + e) * 32 + c * 8);
            *(float4*)(wv + 4) = *(const float4*)(wl + (cin * 8 + e) * 32 + c * 8 + 4);
            #pragma unroll
            for (int jj = 0; jj < 4; ++jj) {
                const int o = 4 * jj;
                acc[jj] += xr[o]*wv[0]   + xr[o+1]*wv[1] + xr[o+2]*wv[2]
                         + xr[o+3]*wv[3] + xr[o+4]*wv[4] + xr[o+5]*wv[5]
                         + xr[o+6]*wv[6] + xr[o+7]*wv[7];
            }
        }
    }
    *(float4*)(u1 + (size_t)t * 16384 + n * 256 + c * 64 + i * 8 + jh * 4) =
        make_float4(acc[0], acc[1], acc[2], acc[3]);
}

// ---------------- k2: scan1, single 100-deep batch, in-place ----------------
__global__ __launch_bounds__(64) void k2_scan(float* __restrict__ u) {
    const int id = blockIdx.x * 64 + threadIdx.x;
    const float a = DECAY;
    float* p = u + id;
    float v[100];
    #pragma unroll
    for (int k = 0; k < 100; ++k) v[k] = p[(size_t)k * 16384];
    float psp = 0.f, r = 0.f;
    #pragma unroll
    for (int k = 0; k < 100; ++k) {
        psp = a * psp + v[k];
        const float vv = psp - r;
        const float s = (vv >= 1.f) ? 1.f : 0.f;
        r = a * (r + s);
        p[(size_t)k * 16384] = s;
    }
}

// ---------------- k3: conv2+pool2 as 4x4 stride-2 conv ----------------
// 8 frames/block (32 thr each). Tile/frame 660 floats, pitch 16, perm rows.
__global__ __launch_bounds__(256) void k3(const float* __restrict__ s1,
        const float* __restrict__ wl2g, float* __restrict__ u2) {
    __shared__ __align__(16) float xs[8 * 660];
    __shared__ __align__(16) float wl[544];
    const int tid = threadIdx.x, sub = tid >> 5, l = tid & 31;

    for (int m = tid; m < 136; m += 256)
        *(float4*)(wl + 4 * m) = *(const float4*)(wl2g + 4 * m);

    float* xt = xs + sub * 660;
    float4* fz = (float4*)xt;
    for (int m = l; m < 160; m += 32) fz[m] = make_float4(0.f, 0.f, 0.f, 0.f);

    const int frame = blockIdx.x * 8 + sub;       // = t*64 + n (s1 is t-major)
    const int t = frame >> 6, n = frame & 63;
    const float* fr = s1 + (size_t)t * 16384 + n * 256;
    {   // stage 8x8x4cin; row r=row+1 at perm(r)=(r&1)*5+(r>>1), cols +4 phys
        const int cin = l >> 3, row = l & 7;
        const int r = row + 1;
        const int pr = (r & 1) * 5 + (r >> 1);
        const float4 v0 = *(const float4*)(fr + cin * 64 + row * 8);
        const float4 v1 = *(const float4*)(fr + cin * 64 + row * 8 + 4);
        *(float4*)(xt + cin * 160 + pr * 16 + 4) = v0;
        *(float4*)(xt + cin * 160 + pr * 16 + 8) = v1;
    }
    __syncthreads();

    const int c2 = l >> 2, i = l & 3;
    float acc[4] = {0.f, 0.f, 0.f, 0.f};
    const float* wb = wl + c2 * 68;
    const float* tb = xt + i * 16;
    #pragma unroll
    for (int cin = 0; cin < 4; ++cin) {
        #pragma unroll
        for (int e = 0; e < 4; ++e) {
            const int C = cin * 160 + ((e & 1) * 5 + (e >> 1)) * 16;
            float xr[16];
            #pragma unroll
            for (int b = 0; b < 4; ++b)
                *(float4*)(xr + 4 * b) = *(const float4*)(tb + C + 4 * b);
            float wv[4];
            *(float4*)(wv) = *(const float4*)(wb + cin * 16 + e * 4);
            #pragma unroll
            for (int j = 0; j < 4; ++j) {
                #pragma unroll
                for (int f = 0; f < 4; ++f)
                    acc[j] += xr[2 * j + f + 3] * wv[f];
            }
        }
    }
    *(float4*)(u2 + (size_t)t * 8192 + n * 128 + c2 * 16 + i * 4) =
        make_float4(acc[0], acc[1], acc[2], acc[3]);
}

// ---------------- k45: scan2 + dense, fused ----------------
// one block per n (64 blocks x 128 thr). Spikes stay in LDS; exact shuffle tree.
__global__ __launch_bounds__(128, 2) void k45(const float* __restrict__ u2,
        const float* __restrict__ lw, float* __restrict__ out) {
    __shared__ float ls[25 * 128];
    const int f = threadIdx.x, n = blockIdx.x;
    const int wave = f >> 6, l = f & 63;
    const float a = DECAY;
    const float w0 = lw[l], w1v = lw[64 + l], w2v = lw[128 + l], w3v = lw[192 + l];
    float psp = 0.f, r = 0.f;
    const float* p = u2 + n * 128 + f;
    #pragma unroll 1
    for (int t0 = 0; t0 < 100; t0 += 25) {
        float v[25];
        #pragma unroll
        for (int k = 0; k < 25; ++k) v[k] = p[(size_t)(t0 + k) * 8192];
        #pragma unroll
        for (int k = 0; k < 25; ++k) {
            psp = a * psp + v[k];
            const float vv = psp - r;
            const float s = (vv >= 1.f) ? 1.f : 0.f;
            r = a * (r + s);
            ls[k * 128 + f] = s;
        }
        __syncthreads();
        const int base = wave ? 13 : 0, cnt = wave ? 12 : 13;
        for (int q = 0; q < cnt; ++q) {
            const int k = base + q;
            const float sa = ls[k * 128 + l], sb = ls[k * 128 + 64 + l];
            float a0 = sa * w0 + sb * w1v;
            float a1 = sa * w2v + sb * w3v;
            #pragma unroll
            for (int off = 32; off > 0; off >>= 1) {
                a0 += __shfl_down(a0, off);
                a1 += __shfl_down(a1, off);
            }
            if (l == 0) {
                const int tt = t0 + k;
                out[n * 200 + tt * 2]     = a0;
                out[n * 200 + tt * 2 + 1] = a1;
            }
        }
        __syncthreads();
    }
}

extern "C" void kernel_launch(void* const* d_in, const int* in_sizes, int n_in,
                              void* d_out, int out_size, void* d_ws, size_t ws_size,
                              hipStream_t stream) {
    const float* x   = (const float*)d_in[0];
    const float* w1  = (const float*)d_in[1];
    const float* w2  = (const float*)d_in[2];
    const float* lw  = (const float*)d_in[3];
    const float* wp1 = (const float*)d_in[4];
    const float* wp2 = (const float*)d_in[5];

    float* u1  = (float*)d_ws;           // 1,638,400 floats (in-place -> s1)
    float* u2  = u1 + 1638400;           //   819,200 floats (pre-scan only)
    float* wl1 = u2 + 819200;            //       512 floats
    float* wl2 = wl1 + 512;              //       544 floats
    float* out = (float*)d_out;          // (64,100,2)

    k0_fold<<<1, 128, 0, stream>>>(w1, w2, wp1, wp2, wl1, wl2);
    k1<<<6400, 64, 0, stream>>>(x, wl1, u1);
    k2_scan<<<256, 64, 0, stream>>>(u1);
    k3<<<800, 256, 0, stream>>>(u1, wl2, u2);
    k45<<<64, 128, 0, stream>>>(u2, lw, out);
}

// Round 7
// 140.558 us; speedup vs baseline: 1.2000x; 1.0216x over previous
//
#include <hip/hip_runtime.h>

// SLAYER SNN forward, MI355X. Round 7.
// Change vs R6: k1 inner loop e-split across lane pairs.
//   lane=(cp,i,jh,eh): each lane computes partial sums over e in {4eh..4eh+3}
//   for 2 c-channels x 4 j; partners (lane^1) butterfly-add at the end.
//   LDS instr/frame: 112 -> 72 (x-reads halved); FMA count unchanged (512/lane).
// k0/k2/k3/k45 unchanged from round 6 (passed, absmax 0.0).

#define DECAY 0.9048374180359595f   // exp(-1/10)

// ---------------- k0: fold weights ----------------
// wl1[(cin*8 + e)*32 + c*8 + f], e,f in 0..7  (512 floats)
// wl2[c2*68 + cin*16 + e*4 + f]               (544 floats incl. unused pads)
__global__ __launch_bounds__(128) void k0_fold(const float* __restrict__ w1,
        const float* __restrict__ w2, const float* __restrict__ wp1,
        const float* __restrict__ wp2, float* __restrict__ wl1,
        float* __restrict__ wl2) {
    const int tid = threadIdx.x;
    const float p1 = wp1[0], p2 = wp2[0];
    for (int idx = tid; idx < 512; idx += 128) {
        const int f = idx & 7, c = (idx >> 3) & 3, e = (idx >> 5) & 7, cin = idx >> 8;
        const int cc = c * 2 + cin;
        int alo = e - 3; if (alo < 0) alo = 0;
        int ahi = e;     if (ahi > 4) ahi = 4;
        int blo = f - 3; if (blo < 0) blo = 0;
        int bhi = f;     if (bhi > 4) bhi = 4;
        float s = 0.f;
        for (int a = alo; a <= ahi; ++a)
            for (int b = blo; b <= bhi; ++b)
                s += w1[cc * 25 + a * 5 + b];
        wl1[(cin * 8 + e) * 32 + c * 8 + f] = s * p1;
    }
    for (int idx = tid; idx < 512; idx += 128) {
        const int c2 = idx & 7, f = (idx >> 3) & 3, e = (idx >> 5) & 3, cin = idx >> 7;
        int alo = e - 1; if (alo < 0) alo = 0;
        int ahi = e;     if (ahi > 2) ahi = 2;
        int blo = f - 1; if (blo < 0) blo = 0;
        int bhi = f;     if (bhi > 2) bhi = 2;
        float s = 0.f;
        for (int aa = alo; aa <= ahi; ++aa)
            for (int bb = blo; bb <= bhi; ++bb)
                s += w2[((c2 * 4 + cin) * 3 + aa) * 3 + bb];
        wl2[c2 * 68 + cin * 16 + e * 4 + f] = s * p2;
    }
}

// ---------------- k1: conv1+pool1, 8x8-tap stride-4 ----------------
// grid 6400 x 64, one frame per block. Tile: [cin][36 prow x 36 col],
// perm(r)=(r&3)*9+(r>>2) bijective on r=0..35. Logical x row R (-2..33) at
// prow perm(R+2); logical col C (-2..33) at phys col C+2.
// Halo rows r{0,1,34,35} -> prows {0,9,26,35}; halo cols phys {0,1},{34,35}.
// Compute: lane=(cp,i,jh,eh); e=4*eh+et; x row 4i+e-2 -> prow et*9+(i+eh).
// Lanes with equal i+eh read identical rows (broadcast); banks <=~2-way.
__global__ __launch_bounds__(64) void k1(const float* __restrict__ x,
        const float* __restrict__ wg, float* __restrict__ u1) {
    __shared__ __align__(16) float xs[2 * 1296];   // 10.1 KB
    __shared__ __align__(16) float wl[512];        // 2 KB
    const int lane = threadIdx.x;
    const int frame = blockIdx.x;                  // = n*100 + t (x is n-major)
    const int n = frame / 100, t = frame % 100;

    // folded weights global->LDS, coalesced (2 float4/lane)
    *(float4*)(wl + 4 * lane)       = *(const float4*)(wg + 4 * lane);
    *(float4*)(wl + 256 + 4 * lane) = *(const float4*)(wg + 256 + 4 * lane);

    // zero halo rows: 2 cin x prows {0,9,26,35} x 9 float4 = 72 float4
    #pragma unroll
    for (int m0 = 0; m0 < 128; m0 += 64) {
        const int m = m0 + lane;
        if (m < 72) {
            const int cin = m / 36, rem = m % 36;
            const int rr = rem / 9, q4 = rem % 9;
            const int pr = (rr == 0) ? 0 : (rr == 1) ? 9 : (rr == 2) ? 26 : 35;
            *(float4*)(xs + cin * 1296 + pr * 36 + q4 * 4) = make_float4(0.f, 0.f, 0.f, 0.f);
        }
    }
    // zero halo cols: 2 cin x 36 prows x 2 sides (float2 at phys col 0 / 34)
    #pragma unroll
    for (int m0 = 0; m0 < 192; m0 += 64) {
        const int m = m0 + lane;
        if (m < 144) {
            const int cin = m / 72, rem = m % 72;
            const int side = rem & 1, pr = rem >> 1;
            *(float2*)(xs + cin * 1296 + pr * 36 + side * 34) = make_float2(0.f, 0.f);
        }
    }
    // stage frame: 512 float4, 8 per lane, coalesced
    const float4* xg = (const float4*)(x + (size_t)frame * 2048);
    #pragma unroll
    for (int q = 0; q < 8; ++q) {
        const int m = q * 64 + lane;
        const float4 v = xg[m];
        const int li = 4 * m;
        const int cin = li >> 10, row = (li >> 5) & 31, col = li & 31;
        const int r = row + 2;
        const int pr = (r & 3) * 9 + (r >> 2);
        float* d = xs + cin * 1296 + pr * 36 + col + 2;
        *(float2*)(d)     = make_float2(v.x, v.y);
        *(float2*)(d + 2) = make_float2(v.z, v.w);
    }
    __syncthreads();

    // lane decomposition for compute
    const int cp = lane >> 5;          // c-pair: covers c = 2cp, 2cp+1
    const int i  = (lane >> 2) & 7;
    const int jh = (lane >> 1) & 1;
    const int eh = lane & 1;           // e-half; partner = lane^1

    float acc[2][4] = {{0.f, 0.f, 0.f, 0.f}, {0.f, 0.f, 0.f, 0.f}};  // [cl][jj]
    const float* tb = xs + (i + eh) * 36 + jh * 16;
    #pragma unroll
    for (int cin = 0; cin < 2; ++cin) {
        #pragma unroll
        for (int et = 0; et < 4; ++et) {
            // x row 4i + (4eh+et) - 2 -> prow et*9 + (i+eh); (i+eh) is in tb
            const int ro = cin * 1296 + et * 9 * 36;
            float xr[20];
            #pragma unroll
            for (int b = 0; b < 5; ++b)
                *(float4*)(xr + 4 * b) = *(const float4*)(tb + ro + 4 * b);
            float wv[16];
            const float* wp = wl + (cin * 8 + eh * 4 + et) * 32 + cp * 16;
            #pragma unroll
            for (int q = 0; q < 4; ++q)
                *(float4*)(wv + 4 * q) = *(const float4*)(wp + 4 * q);
            #pragma unroll
            for (int cl = 0; cl < 2; ++cl) {
                #pragma unroll
                for (int jj = 0; jj < 4; ++jj) {
                    const int o = 4 * jj;
                    acc[cl][jj] += xr[o]*wv[cl*8]     + xr[o+1]*wv[cl*8+1]
                                 + xr[o+2]*wv[cl*8+2] + xr[o+3]*wv[cl*8+3]
                                 + xr[o+4]*wv[cl*8+4] + xr[o+5]*wv[cl*8+5]
                                 + xr[o+6]*wv[cl*8+6] + xr[o+7]*wv[cl*8+7];
                }
            }
        }
    }
    // butterfly over eh-partners: both lanes get full e-sum (fp add commutes)
    #pragma unroll
    for (int cl = 0; cl < 2; ++cl)
        #pragma unroll
        for (int jj = 0; jj < 4; ++jj)
            acc[cl][jj] += __shfl_xor(acc[cl][jj], 1);

    // lane writes channel c = 2cp + eh (its cl = eh slice)
    const float o0 = eh ? acc[1][0] : acc[0][0];
    const float o1 = eh ? acc[1][1] : acc[0][1];
    const float o2 = eh ? acc[1][2] : acc[0][2];
    const float o3 = eh ? acc[1][3] : acc[0][3];
    *(float4*)(u1 + (size_t)t * 16384 + n * 256 + (2 * cp + eh) * 64 + i * 8 + jh * 4) =
        make_float4(o0, o1, o2, o3);
}

// ---------------- k2: scan1, single 100-deep batch, in-place ----------------
__global__ __launch_bounds__(64) void k2_scan(float* __restrict__ u) {
    const int id = blockIdx.x * 64 + threadIdx.x;
    const float a = DECAY;
    float* p = u + id;
    float v[100];
    #pragma unroll
    for (int k = 0; k < 100; ++k) v[k] = p[(size_t)k * 16384];
    float psp = 0.f, r = 0.f;
    #pragma unroll
    for (int k = 0; k < 100; ++k) {
        psp = a * psp + v[k];
        const float vv = psp - r;
        const float s = (vv >= 1.f) ? 1.f : 0.f;
        r = a * (r + s);
        p[(size_t)k * 16384] = s;
    }
}

// ---------------- k3: conv2+pool2 as 4x4 stride-2 conv ----------------
// 8 frames/block (32 thr each). Tile/frame 660 floats, pitch 16, perm rows.
__global__ __launch_bounds__(256) void k3(const float* __restrict__ s1,
        const float* __restrict__ wl2g, float* __restrict__ u2) {
    __shared__ __align__(16) float xs[8 * 660];
    __shared__ __align__(16) float wl[544];
    const int tid = threadIdx.x, sub = tid >> 5, l = tid & 31;

    for (int m = tid; m < 136; m += 256)
        *(float4*)(wl + 4 * m) = *(const float4*)(wl2g + 4 * m);

    float* xt = xs + sub * 660;
    float4* fz = (float4*)xt;
    for (int m = l; m < 160; m += 32) fz[m] = make_float4(0.f, 0.f, 0.f, 0.f);

    const int frame = blockIdx.x * 8 + sub;       // = t*64 + n (s1 is t-major)
    const int t = frame >> 6, n = frame & 63;
    const float* fr = s1 + (size_t)t * 16384 + n * 256;
    {   // stage 8x8x4cin; row r=row+1 at perm(r)=(r&1)*5+(r>>1), cols +4 phys
        const int cin = l >> 3, row = l & 7;
        const int r = row + 1;
        const int pr = (r & 1) * 5 + (r >> 1);
        const float4 v0 = *(const float4*)(fr + cin * 64 + row * 8);
        const float4 v1 = *(const float4*)(fr + cin * 64 + row * 8 + 4);
        *(float4*)(xt + cin * 160 + pr * 16 + 4) = v0;
        *(float4*)(xt + cin * 160 + pr * 16 + 8) = v1;
    }
    __syncthreads();

    const int c2 = l >> 2, i = l & 3;
    float acc[4] = {0.f, 0.f, 0.f, 0.f};
    const float* wb = wl + c2 * 68;
    const float* tb = xt + i * 16;
    #pragma unroll
    for (int cin = 0; cin < 4; ++cin) {
        #pragma unroll
        for (int e = 0; e < 4; ++e) {
            const int C = cin * 160 + ((e & 1) * 5 + (e >> 1)) * 16;
            float xr[16];
            #pragma unroll
            for (int b = 0; b < 4; ++b)
                *(float4*)(xr + 4 * b) = *(const float4*)(tb + C + 4 * b);
            float wv[4];
            *(float4*)(wv) = *(const float4*)(wb + cin * 16 + e * 4);
            #pragma unroll
            for (int j = 0; j < 4; ++j) {
                #pragma unroll
                for (int f = 0; f < 4; ++f)
                    acc[j] += xr[2 * j + f + 3] * wv[f];
            }
        }
    }
    *(float4*)(u2 + (size_t)t * 8192 + n * 128 + c2 * 16 + i * 4) =
        make_float4(acc[0], acc[1], acc[2], acc[3]);
}

// ---------------- k45: scan2 + dense, fused ----------------
// one block per n (64 blocks x 128 thr). Spikes stay in LDS; exact shuffle tree.
__global__ __launch_bounds__(128, 2) void k45(const float* __restrict__ u2,
        const float* __restrict__ lw, float* __restrict__ out) {
    __shared__ float ls[25 * 128];
    const int f = threadIdx.x, n = blockIdx.x;
    const int wave = f >> 6, l = f & 63;
    const float a = DECAY;
    const float w0 = lw[l], w1v = lw[64 + l], w2v = lw[128 + l], w3v = lw[192 + l];
    float psp = 0.f, r = 0.f;
    const float* p = u2 + n * 128 + f;
    #pragma unroll 1
    for (int t0 = 0; t0 < 100; t0 += 25) {
        float v[25];
        #pragma unroll
        for (int k = 0; k < 25; ++k) v[k] = p[(size_t)(t0 + k) * 8192];
        #pragma unroll
        for (int k = 0; k < 25; ++k) {
            psp = a * psp + v[k];
            const float vv = psp - r;
            const float s = (vv >= 1.f) ? 1.f : 0.f;
            r = a * (r + s);
            ls[k * 128 + f] = s;
        }
        __syncthreads();
        const int base = wave ? 13 : 0, cnt = wave ? 12 : 13;
        for (int q = 0; q < cnt; ++q) {
            const int k = base + q;
            const float sa = ls[k * 128 + l], sb = ls[k * 128 + 64 + l];
            float a0 = sa * w0 + sb * w1v;
            float a1 = sa * w2v + sb * w3v;
            #pragma unroll
            for (int off = 32; off > 0; off >>= 1) {
                a0 += __shfl_down(a0, off);
                a1 += __shfl_down(a1, off);
            }
            if (l == 0) {
                const int tt = t0 + k;
                out[n * 200 + tt * 2]     = a0;
                out[n * 200 + tt * 2 + 1] = a1;
            }
        }
        __syncthreads();
    }
}

extern "C" void kernel_launch(void* const* d_in, const int* in_sizes, int n_in,
                              void* d_out, int out_size, void* d_ws, size_t ws_size,
                              hipStream_t stream) {
    const float* x   = (const float*)d_in[0];
    const float* w1  = (const float*)d_in[1];
    const float* w2  = (const float*)d_in[2];
    const float* lw  = (const float*)d_in[3];
    const float* wp1 = (const float*)d_in[4];
    const float* wp2 = (const float*)d_in[5];

    float* u1  = (float*)d_ws;           // 1,638,400 floats (in-place -> s1)
    float* u2  = u1 + 1638400;           //   819,200 floats (pre-scan only)
    float* wl1 = u2 + 819200;            //       512 floats
    float* wl2 = wl1 + 512;              //       544 floats
    float* out = (float*)d_out;          // (64,100,2)

    k0_fold<<<1, 128, 0, stream>>>(w1, w2, wp1, wp2, wl1, wl2);
    k1<<<6400, 64, 0, stream>>>(x, wl1, u1);
    k2_scan<<<256, 64, 0, stream>>>(u1);
    k3<<<800, 256, 0, stream>>>(u1, wl2, u2);
    k45<<<64, 128, 0, stream>>>(u2, lw, out);
}